// Round 15
// baseline (197.861 us; speedup 1.0000x reference)
//
#include <hip/hip_runtime.h>
#include <stdint.h>

// Problem constants: b=16, f=8, n=256, N=2048, dim=512, H=8, DH=64, keys/group=257
#define ATT_SCALE 0.125f

typedef __attribute__((ext_vector_type(8))) short bhalf8;       // 8 bf16 = 4 VGPR (MFMA A/B frag)
typedef __attribute__((ext_vector_type(4))) float floatx4;      // 16x16 MFMA C/D frag
typedef __attribute__((ext_vector_type(16))) float floatx16;    // 32x32 MFMA C/D frag
typedef __attribute__((ext_vector_type(8))) unsigned short ush8;

__device__ __forceinline__ unsigned short f2bf(float f) {
  union { float f; unsigned int u; } v; v.f = f;
  unsigned int r = v.u + 0x7fffu + ((v.u >> 16) & 1u);  // RNE
  return (unsigned short)(r >> 16);
}
__device__ __forceinline__ float bf2f(unsigned short u) {
  union { unsigned int u; float f; } v; v.u = ((unsigned int)u) << 16;
  return v.f;
}
// {lo=bf16(a), hi=bf16(b)} RNE — verified safe (round 6/9)
__device__ __forceinline__ unsigned int pk2(float a, float b) {
  unsigned int r;
  asm("v_cvt_pk_bf16_f32 %0, %1, %2" : "=v"(r) : "v"(a), "v"(b));
  return r;
}
__device__ __forceinline__ void glds16(const void* g, void* l) {
  __builtin_amdgcn_global_load_lds(
      (__attribute__((address_space(1))) void*)g,
      (__attribute__((address_space(3))) void*)l, 16, 0, 0);
}

// ======= prep: conv_x grid-stride (blocks 0..4095) | conv_w (4096..7167) | ext_qkv (7168..7263) =======
__global__ __launch_bounds__(256) void k_prep(
    const float* __restrict__ x, const float* __restrict__ ext,
    const float* __restrict__ Wq, const float* __restrict__ Wk,
    const float* __restrict__ Wv, const float* __restrict__ Wo,
    const float* __restrict__ bq, const float* __restrict__ bk, const float* __restrict__ bv,
    unsigned short* __restrict__ Xbf, unsigned short* __restrict__ Wqkvt,
    unsigned short* __restrict__ Wot, float* __restrict__ biasqkv,
    float* __restrict__ EQKV) {
  __shared__ float xs[512];
  int bid = blockIdx.x, tid = threadIdx.x;
  if (bid < 4096) {
    // ---- conv_x: fp32 -> bf16, grid-stride, 16 elems/thread ----
    #pragma unroll
    for (int it = 0; it < 4; ++it) {
      int i = (it * 4096 + bid) * 256 + tid;
      float4 v = ((const float4*)x)[i];
      ((uint2*)Xbf)[i] = make_uint2(pk2(v.x, v.y), pk2(v.z, v.w));
    }
  } else if (bid < 7168) {
    // ---- conv_w: transposed bf16 weights + bias concat ----
    int idx = (bid - 4096) * 256 + tid;
    {
      int nn = idx >> 9, k = idx & 511;
      const float* W = (nn < 512) ? Wq : ((nn < 1024) ? Wk : Wv);
      int n = nn & 511;
      Wqkvt[idx] = f2bf(W[k * 512 + n]);
    }
    if (idx < 512 * 512) {
      int n = idx >> 9, k = idx & 511;
      Wot[idx] = f2bf(Wo[k * 512 + n]);
    }
    if (idx < 1536) {
      biasqkv[idx] = (idx < 512) ? bq[idx] : ((idx < 1024) ? bk[idx - 512] : bv[idx - 1024]);
    }
  } else {
    // ---- ext_qkv: EQKV[16][1536] fp32 (q pre-scaled) ----
    int bid2 = bid - 7168;
    int b = bid2 / 6, c = bid2 % 6;
    int nn = c * 256 + tid;
    xs[tid] = ext[b * 512 + tid];
    xs[256 + tid] = ext[b * 512 + 256 + tid];
    __syncthreads();
    const float* W; const float* bias; float scale = 1.f; int n;
    if (nn < 512)      { W = Wq; bias = bq; n = nn;        scale = ATT_SCALE; }
    else if (nn < 1024){ W = Wk; bias = bk; n = nn - 512; }
    else               { W = Wv; bias = bv; n = nn - 1024; }
    float acc = 0.f;
    #pragma unroll 8
    for (int k = 0; k < 512; ++k) acc += xs[k] * W[k * 512 + n];
    EQKV[b * 1536 + nn] = (acc + bias[n]) * scale;
  }
}

// =============== 128x128-tile MFMA GEMM, m97 2-barrier loop, BK=64, XOR-swizzled LDS ===============
// (round-5/9/12 proven: ~60 us, MfmaUtil 36%, 0 conflicts). launch_bounds (256,2): measured best
// ((256,4) spilled: cap 128 < 144 regs; (256,3) no-spill but occupancy unchanged -> resource-limited).
__global__ __launch_bounds__(256, 2) void k_gemm_qkv(
    const unsigned short* __restrict__ A, const unsigned short* __restrict__ B,
    const float* __restrict__ bias, unsigned short* __restrict__ C) {
  __shared__ __align__(16) unsigned short S[16384];  // A 16 KB + B 16 KB
  int tid = threadIdx.x, lane = tid & 63, wv = tid >> 6;
  int lo = lane & 15, hi = lane >> 4;
  int waveM = wv >> 1, waveN = wv & 1;

  int nwg = gridDim.x;  // 3072
  int wg = (blockIdx.x & 7) * (nwg >> 3) + (blockIdx.x >> 3);
  int bm = wg / 12, bn = wg % 12;

  const unsigned short* Ab = A + (size_t)bm * 128 * 512;
  const unsigned short* Bb = B + (size_t)bn * 128 * 512;
  unsigned short* lA = S;
  unsigned short* lB = S + 8192;

  floatx4 acc[4][4];
  #pragma unroll
  for (int m = 0; m < 4; ++m)
    #pragma unroll
    for (int n = 0; n < 4; ++n) acc[m][n] = floatx4{0.f, 0.f, 0.f, 0.f};

  for (int kt = 0; kt < 8; ++kt) {
    __syncthreads();
    #pragma unroll
    for (int i = 0; i < 4; ++i) {
      int chunk = i * 256 + tid;
      int row = chunk >> 3, slot = chunk & 7;
      glds16(Ab + (size_t)row * 512 + kt * 64 + ((slot ^ (row & 7)) << 3),
             lA + (size_t)(i * 256 + wv * 64) * 8);
    }
    #pragma unroll
    for (int i = 0; i < 4; ++i) {
      int chunk = i * 256 + tid;
      int row = chunk >> 3, slot = chunk & 7;
      glds16(Bb + (size_t)row * 512 + kt * 64 + ((slot ^ (row & 7)) << 3),
             lB + (size_t)(i * 256 + wv * 64) * 8);
    }
    __syncthreads();

    bhalf8 af[4][2], bf4[4][2];
    #pragma unroll
    for (int m = 0; m < 4; ++m) {
      int row = waveM * 64 + m * 16 + lo;
      #pragma unroll
      for (int ks = 0; ks < 2; ++ks)
        af[m][ks] = *(const bhalf8*)(lA + (size_t)row * 64 + (((ks * 4 + hi) ^ (row & 7)) << 3));
    }
    #pragma unroll
    for (int n = 0; n < 4; ++n) {
      int row = waveN * 64 + n * 16 + lo;
      #pragma unroll
      for (int ks = 0; ks < 2; ++ks)
        bf4[n][ks] = *(const bhalf8*)(lB + (size_t)row * 64 + (((ks * 4 + hi) ^ (row & 7)) << 3));
    }
    #pragma unroll
    for (int m = 0; m < 4; ++m)
      #pragma unroll
      for (int n = 0; n < 4; ++n) {
        acc[m][n] = __builtin_amdgcn_mfma_f32_16x16x32_bf16(af[m][0], bf4[n][0], acc[m][n], 0, 0, 0);
        acc[m][n] = __builtin_amdgcn_mfma_f32_16x16x32_bf16(af[m][1], bf4[n][1], acc[m][n], 0, 0, 0);
      }
  }

  #pragma unroll
  for (int m = 0; m < 4; ++m) {
    int row0 = bm * 128 + waveM * 64 + m * 16 + hi * 4;
    #pragma unroll
    for (int n = 0; n < 4; ++n) {
      int col = bn * 128 + waveN * 64 + n * 16 + lo;
      float bb = bias[col];
      #pragma unroll
      for (int r = 0; r < 4; ++r) {
        float v = acc[m][n][r] + bb;
        if (col < 512) v *= ATT_SCALE;
        C[(size_t)(row0 + r) * 1536 + col] = f2bf(v);
      }
    }
  }
}

// ---------------- attention: blocks <1024 = main attn v4; blocks >=1024 = external-query attn ----------------
// VTC=266: row stride 133 dwords (odd) -> PV b128 reads hit 32 distinct banks (was 296: 4-way).
#define VTC 266
__global__ __launch_bounds__(512, 4) void k_attn_all(
    const unsigned short* __restrict__ QKV,   // [32768][1536] bf16 (q scaled)
    const float* __restrict__ EQKV,           // [16][1536] f32
    unsigned short* __restrict__ mainb,       // [32768][512] bf16
    float* __restrict__ extpre) {             // [16][512] f32
  __shared__ __align__(16) unsigned short Ks[256 * 64];  // rows XOR-swizzled; reused as epilogue buf
  __shared__ __align__(16) unsigned short Vt[64 * VTC];  // [d][key] transposed, local keys only
  __shared__ float kx[64], vx[64];
  int tid = threadIdx.x, lane = tid & 63, wv = tid >> 6;

  if (blockIdx.x >= 1024) {
    // ======== external-query attention, 512 threads, keys 0..256 of chunk j=1 ========
    int eg = blockIdx.x - 1024;
    int b = eg >> 3, h = eg & 7;
    float* qs   = (float*)Ks;          // 64
    float* ps   = qs + 64;             // 257
    float* redm = ps + 257;            // 8
    float* reds = redm + 8;            // 8
    float (*acc8)[64] = (float (*)[64])(reds + 8);  // 8x64
    if (tid < 64) qs[tid] = EQKV[b * 1536 + h * 64 + tid];
    __syncthreads();
    const size_t base = (size_t)b * 2048 + 256;
    float s = -1e30f;
    if (tid < 257) {
      s = 0.f;
      if (tid == 0) {
        const float* kr = EQKV + b * 1536 + 512 + h * 64;
        #pragma unroll 8
        for (int d = 0; d < 64; ++d) s += qs[d] * kr[d];
      } else {
        const unsigned short* kr = QKV + (base + tid - 1) * 1536 + 512 + h * 64;
        #pragma unroll
        for (int c = 0; c < 8; ++c) {
          ush8 kv = *(const ush8*)(kr + c * 8);
          #pragma unroll
          for (int u = 0; u < 8; ++u) s += qs[c * 8 + u] * bf2f(kv[u]);
        }
      }
    }
    float lmax = s;
    for (int d = 1; d < 64; d <<= 1) lmax = fmaxf(lmax, __shfl_xor(lmax, d, 64));
    if (lane == 0) redm[wv] = lmax;
    __syncthreads();
    float M = redm[0];
    #pragma unroll
    for (int w = 1; w < 8; ++w) M = fmaxf(M, redm[w]);
    float p = 0.f;
    if (tid < 257) { p = __expf(s - M); ps[tid] = p; }
    float lsum = p;
    for (int d = 1; d < 64; d <<= 1) lsum += __shfl_xor(lsum, d, 64);
    if (lane == 0) reds[wv] = lsum;
    __syncthreads();
    float Ssum = reds[0] + reds[1] + reds[2] + reds[3] + reds[4] + reds[5] + reds[6] + reds[7];
    int d = tid & 63, part = tid >> 6;
    float acc = 0.f;
    for (int key = part; key < 257; key += 8) {
      float vv = (key == 0) ? EQKV[b * 1536 + 1024 + h * 64 + d]
                            : bf2f(QKV[(base + key - 1) * 1536 + 1024 + h * 64 + d]);
      acc += ps[key] * vv;
    }
    acc8[part][d] = acc;
    __syncthreads();
    if (tid < 64) {
      float r = (acc8[0][tid] + acc8[1][tid] + acc8[2][tid] + acc8[3][tid] +
                 acc8[4][tid] + acc8[5][tid] + acc8[6][tid] + acc8[7][tid]) / Ssum;
      extpre[b * 512 + h * 64 + tid] = r;
    }
    return;
  }

  // ======== main attention v4: 8 warps x 32 queries; local keys 0..255; external key in-register ========
  int g = blockIdx.x;
  int b = g >> 6, h = (g >> 3) & 7, j = g & 7;
  int ql = lane & 31, hb = lane >> 5;
  const size_t rowbase = (size_t)b * 2048 + (size_t)j * 256;
  const unsigned short* Kg = QKV + rowbase * 1536 + 512 + h * 64;
  const unsigned short* Vg = QKV + rowbase * 1536 + 1024 + h * 64;

  int qbase = wv * 32;
  const unsigned short* qp = QKV + (rowbase + qbase + ql) * 1536 + h * 64 + hb * 8;
  bhalf8 qf[4];
  #pragma unroll
  for (int c = 0; c < 4; ++c) qf[c] = *(const bhalf8*)(qp + c * 16);

  // stage K rows 0..255 via global_load_lds, pre-swizzled source (linear dest)
  {
    int keybase = wv * 32;
    #pragma unroll
    for (int i = 0; i < 4; ++i) {
      int key = keybase + i * 8 + (lane >> 3);
      int slot = lane & 7;
      const unsigned short* src =
          Kg + (size_t)key * 1536 + (((slot * 16) ^ ((key & 7) << 4)) >> 1);
      glds16(src, &Ks[(size_t)(keybase + i * 8) * 64]);
    }
  }
  // stage V transposed, pair-packed: unit = (key-pair, d-group); writes are contiguous u32
  for (int c = tid; c < 1024; c += 512) {
    int kp = (c & 127) * 2, d0 = (c >> 7) * 8;
    ush8 v0 = *(const ush8*)(Vg + (size_t)kp * 1536 + d0);
    ush8 v1 = *(const ush8*)(Vg + (size_t)(kp + 1) * 1536 + d0);
    #pragma unroll
    for (int u = 0; u < 8; ++u)
      *(unsigned int*)(Vt + (size_t)(d0 + u) * VTC + kp) =
          (unsigned int)(unsigned short)v0[u] | ((unsigned int)(unsigned short)v1[u] << 16);
  }
  if (tid < 64) {
    kx[tid] = EQKV[b * 1536 + 512 + h * 64 + tid];
    vx[tid] = EQKV[b * 1536 + 1024 + h * 64 + tid];
  }
  __syncthreads();

  // external-key score: lane holds q[ql] dims {c*16+hb*8 .. +7}; partner has the rest
  float part = 0.f;
  #pragma unroll
  for (int c = 0; c < 4; ++c)
    #pragma unroll
    for (int u = 0; u < 8; ++u)
      part += bf2f((unsigned short)qf[c][u]) * kx[c * 16 + hb * 8 + u];
  float m = part + __shfl_xor(part, 32, 64);   // s_ext (q pre-scaled)
  float lsum = 1.f;                            // exp(s_ext - m) = 1
  floatx16 o0, o1;
  #pragma unroll
  for (int i = 0; i < 8; ++i) {                // o init = p_ext * v_ext = v_ext
    int d0 = ((2 * i) & 3) + 8 * (i >> 1) + 4 * hb;
    o0[2 * i] = vx[d0];       o0[2 * i + 1] = vx[d0 + 1];
    o1[2 * i] = vx[32 + d0];  o1[2 * i + 1] = vx[32 + d0 + 1];
  }

  #pragma unroll
  for (int t = 0; t < 8; ++t) {
    floatx16 s;
    #pragma unroll
    for (int i = 0; i < 16; ++i) s[i] = 0.f;
    int key = t * 32 + ql;
    __builtin_amdgcn_s_setprio(1);
    #pragma unroll
    for (int c = 0; c < 4; ++c) {
      bhalf8 kf = *(const bhalf8*)((const char*)Ks + key * 128 +
                                   ((c * 32 + hb * 16) ^ ((key & 7) << 4)));
      s = __builtin_amdgcn_mfma_f32_32x32x16_bf16(kf, qf[c], s, 0, 0, 0);
    }
    __builtin_amdgcn_s_setprio(0);
    float mt = s[0];
    #pragma unroll
    for (int r = 1; r < 16; ++r) mt = fmaxf(mt, s[r]);
    mt = fmaxf(mt, __shfl_xor(mt, 32, 64));
    if (!__all(mt - m <= 8.f)) {   // defer-max (T13)
      float mnew = fmaxf(m, mt);
      float corr = __expf(m - mnew);
      lsum *= corr;
      #pragma unroll
      for (int r = 0; r < 16; ++r) { o0[r] *= corr; o1[r] *= corr; }
      m = mnew;
    }
    float p[16]; float ts = 0.f;
    #pragma unroll
    for (int r = 0; r < 16; ++r) { p[r] = __expf(s[r] - m); ts += p[r]; }
    lsum += ts;
    unsigned int pk[8], qk[8];
    #pragma unroll
    for (int i = 0; i < 8; ++i) pk[i] = pk2(p[2 * i], p[2 * i + 1]);
    #pragma unroll
    for (int i = 0; i < 8; ++i) qk[i] = __shfl_xor(pk[i], 32, 64);
    bhalf8 f0, f1;
    unsigned int* f0u = (unsigned int*)&f0;
    unsigned int* f1u = (unsigned int*)&f1;
    if (hb == 0) {
      f0u[0] = pk[0]; f0u[1] = pk[1]; f0u[2] = qk[0]; f0u[3] = qk[1];
      f1u[0] = pk[4]; f1u[1] = pk[5]; f1u[2] = qk[4]; f1u[3] = qk[5];
    } else {
      f0u[0] = qk[2]; f0u[1] = qk[3]; f0u[2] = pk[2]; f0u[3] = pk[3];
      f1u[0] = qk[6]; f1u[1] = qk[7]; f1u[2] = pk[6]; f1u[3] = pk[7];
    }
    {
      const char* vb0 = (const char*)Vt + ((0 * 32 + ql) * VTC + t * 32 + hb * 8) * 2;
      bhalf8 v0 = *(const bhalf8*)vb0;
      bhalf8 v1 = *(const bhalf8*)(vb0 + 32);
      const char* vb1 = (const char*)Vt + ((1 * 32 + ql) * VTC + t * 32 + hb * 8) * 2;
      bhalf8 w0 = *(const bhalf8*)vb1;
      bhalf8 w1 = *(const bhalf8*)(vb1 + 32);
      __builtin_amdgcn_s_setprio(1);
      o0 = __builtin_amdgcn_mfma_f32_32x32x16_bf16(v0, f0, o0, 0, 0, 0);
      o0 = __builtin_amdgcn_mfma_f32_32x32x16_bf16(v1, f1, o0, 0, 0, 0);
      o1 = __builtin_amdgcn_mfma_f32_32x32x16_bf16(w0, f0, o1, 0, 0, 0);
      o1 = __builtin_amdgcn_mfma_f32_32x32x16_bf16(w1, f1, o1, 0, 0, 0);
      __builtin_amdgcn_s_setprio(0);
    }
  }

  lsum += __shfl_xor(lsum, 32, 64);
  float rinv = 1.f / lsum;
  __syncthreads();  // all K reads done; reuse Ks as per-warp transpose buffer
  char* ob = (char*)(Ks + wv * 2048);  // 32q x 64d bf16 = 4KB per warp
  #pragma unroll
  for (int dt = 0; dt < 2; ++dt) {
    #pragma unroll
    for (int i = 0; i < 8; ++i) {
      int d0 = dt * 32 + ((2 * i) & 3) + 8 * (i >> 1) + 4 * hb;
      float a = (dt ? o1[2 * i] : o0[2 * i]) * rinv;
      float c = (dt ? o1[2 * i + 1] : o0[2 * i + 1]) * rinv;
      *(unsigned int*)(ob + ql * 128 + ((d0 * 2) ^ ((ql & 7) << 4))) = pk2(a, c);
    }
  }
  #pragma unroll
  for (int i = 0; i < 4; ++i) {
    int chunk = i * 64 + lane;
    int q = chunk >> 3, slot = chunk & 7;
    bhalf8 vv = *(const bhalf8*)(ob + q * 128 + ((slot * 16) ^ ((q & 7) << 4)));
    *(bhalf8*)(mainb + (rowbase + qbase + q) * 512 + h * 64 + slot * 8) = vv;
  }
}

// ======= output GEMM (wg<1024) | ext_out (wg>=1024): C f32 = mainb * Wo^T + bo =======
__global__ __launch_bounds__(256, 2) void k_gemm_out(
    const unsigned short* __restrict__ A, const unsigned short* __restrict__ B,
    const float* __restrict__ bias, float* __restrict__ C,
    const float* __restrict__ extpre, const float* __restrict__ Wo) {
  __shared__ __align__(16) unsigned short S[16384];
  int tid = threadIdx.x, lane = tid & 63, wv = tid >> 6;
  int nwg = gridDim.x;  // 1056, %8==0
  int wg = (blockIdx.x & 7) * (nwg >> 3) + (blockIdx.x >> 3);

  if (wg >= 1024) {
    // ---- ext_out: out[16M + b*512 + n] = extpre[b] . Wo[:,n] + bo[n] ----
    int idx = wg - 1024;            // 0..31
    int b = idx >> 1, half = idx & 1;
    int n = half * 256 + tid;
    float* xs = (float*)S;
    xs[tid] = extpre[b * 512 + tid];
    xs[256 + tid] = extpre[b * 512 + 256 + tid];
    __syncthreads();
    float acc = bias[n];
    #pragma unroll 8
    for (int k = 0; k < 512; ++k) acc += xs[k] * Wo[k * 512 + n];
    C[16777216 + b * 512 + n] = acc;
    return;
  }

  int lo = lane & 15, hi = lane >> 4;
  int waveM = wv >> 1, waveN = wv & 1;
  int bm = wg / 4, bn = wg % 4;

  const unsigned short* Ab = A + (size_t)bm * 128 * 512;
  const unsigned short* Bb = B + (size_t)bn * 128 * 512;
  unsigned short* lA = S;
  unsigned short* lB = S + 8192;

  floatx4 acc[4][4];
  #pragma unroll
  for (int m = 0; m < 4; ++m)
    #pragma unroll
    for (int n = 0; n < 4; ++n) acc[m][n] = floatx4{0.f, 0.f, 0.f, 0.f};

  for (int kt = 0; kt < 8; ++kt) {
    __syncthreads();
    #pragma unroll
    for (int i = 0; i < 4; ++i) {
      int chunk = i * 256 + tid;
      int row = chunk >> 3, slot = chunk & 7;
      glds16(Ab + (size_t)row * 512 + kt * 64 + ((slot ^ (row & 7)) << 3),
             lA + (size_t)(i * 256 + wv * 64) * 8);
    }
    #pragma unroll
    for (int i = 0; i < 4; ++i) {
      int chunk = i * 256 + tid;
      int row = chunk >> 3, slot = chunk & 7;
      glds16(Bb + (size_t)row * 512 + kt * 64 + ((slot ^ (row & 7)) << 3),
             lB + (size_t)(i * 256 + wv * 64) * 8);
    }
    __syncthreads();

    bhalf8 af[4][2], bf4[4][2];
    #pragma unroll
    for (int m = 0; m < 4; ++m) {
      int row = waveM * 64 + m * 16 + lo;
      #pragma unroll
      for (int ks = 0; ks < 2; ++ks)
        af[m][ks] = *(const bhalf8*)(lA + (size_t)row * 64 + (((ks * 4 + hi) ^ (row & 7)) << 3));
    }
    #pragma unroll
    for (int n = 0; n < 4; ++n) {
      int row = waveN * 64 + n * 16 + lo;
      #pragma unroll
      for (int ks = 0; ks < 2; ++ks)
        bf4[n][ks] = *(const bhalf8*)(lB + (size_t)row * 64 + (((ks * 4 + hi) ^ (row & 7)) << 3));
    }
    #pragma unroll
    for (int m = 0; m < 4; ++m)
      #pragma unroll
      for (int n = 0; n < 4; ++n) {
        acc[m][n] = __builtin_amdgcn_mfma_f32_16x16x32_bf16(af[m][0], bf4[n][0], acc[m][n], 0, 0, 0);
        acc[m][n] = __builtin_amdgcn_mfma_f32_16x16x32_bf16(af[m][1], bf4[n][1], acc[m][n], 0, 0, 0);
      }
  }

  #pragma unroll
  for (int m = 0; m < 4; ++m) {
    int row0 = bm * 128 + waveM * 64 + m * 16 + hi * 4;
    #pragma unroll
    for (int n = 0; n < 4; ++n) {
      int col = bn * 128 + waveN * 64 + n * 16 + lo;
      float bb = bias[col];
      #pragma unroll
      for (int r = 0; r < 4; ++r)
        C[(size_t)(row0 + r) * 512 + col] = acc[m][n][r] + bb;
    }
  }
}

extern "C" void kernel_launch(void* const* d_in, const int* in_sizes, int n_in,
                              void* d_out, int out_size, void* d_ws, size_t ws_size,
                              hipStream_t stream) {
  (void)in_sizes; (void)n_in; (void)out_size; (void)ws_size;
  const float* x   = (const float*)d_in[0];
  const float* ext = (const float*)d_in[1];
  const float* Wq  = (const float*)d_in[2];
  const float* bq  = (const float*)d_in[3];
  const float* Wk  = (const float*)d_in[4];
  const float* bk  = (const float*)d_in[5];
  const float* Wv  = (const float*)d_in[6];
  const float* bv  = (const float*)d_in[7];
  const float* Wo  = (const float*)d_in[8];
  const float* bo  = (const float*)d_in[9];
  float* out = (float*)d_out;

  char* ws = (char*)d_ws;
  size_t off = 0;
  auto take = [&](size_t bytes) { char* p = ws + off; off += (bytes + 255) & ~(size_t)255; return p; };
  unsigned short* Xbf    = (unsigned short*)take((size_t)32768 * 512 * 2);
  unsigned short* Wqkvt  = (unsigned short*)take((size_t)1536 * 512 * 2);
  unsigned short* Wot    = (unsigned short*)take((size_t)512 * 512 * 2);
  float*          biasqkv= (float*)take(1536 * 4);
  float*          EQKV   = (float*)take(16 * 1536 * 4);
  unsigned short* QKVb   = (unsigned short*)take((size_t)32768 * 1536 * 2);
  unsigned short* mainb  = (unsigned short*)take((size_t)32768 * 512 * 2);
  float*          extpre = (float*)take(16 * 512 * 4);

  k_prep<<<7264, 256, 0, stream>>>(x, ext, Wq, Wk, Wv, Wo, bq, bk, bv,
                                   Xbf, Wqkvt, Wot, biasqkv, EQKV);
  k_gemm_qkv<<<3072, 256, 0, stream>>>(Xbf, Wqkvt, biasqkv, QKVb);
  k_attn_all<<<1152, 512, 0, stream>>>(QKVb, EQKV, mainb, extpre);
  k_gemm_out<<<1056, 256, 0, stream>>>(mainb, Wot, bo, out, extpre, Wo);
}

// Round 16
// 180.159 us; speedup vs baseline: 1.0983x; 1.0983x over previous
//
#include <hip/hip_runtime.h>
#include <stdint.h>

// Problem constants: b=16, f=8, n=256, N=2048, dim=512, H=8, DH=64, keys/group=257
#define ATT_SCALE 0.125f

typedef __attribute__((ext_vector_type(8))) short bhalf8;       // 8 bf16 = 4 VGPR (MFMA A/B frag)
typedef __attribute__((ext_vector_type(4))) float floatx4;      // 16x16 MFMA C/D frag
typedef __attribute__((ext_vector_type(16))) float floatx16;    // 32x32 MFMA C/D frag
typedef __attribute__((ext_vector_type(8))) unsigned short ush8;

__device__ __forceinline__ unsigned short f2bf(float f) {
  union { float f; unsigned int u; } v; v.f = f;
  unsigned int r = v.u + 0x7fffu + ((v.u >> 16) & 1u);  // RNE
  return (unsigned short)(r >> 16);
}
__device__ __forceinline__ float bf2f(unsigned short u) {
  union { unsigned int u; float f; } v; v.u = ((unsigned int)u) << 16;
  return v.f;
}
// {lo=bf16(a), hi=bf16(b)} RNE — verified safe (round 6/9)
__device__ __forceinline__ unsigned int pk2(float a, float b) {
  unsigned int r;
  asm("v_cvt_pk_bf16_f32 %0, %1, %2" : "=v"(r) : "v"(a), "v"(b));
  return r;
}
__device__ __forceinline__ void glds16(const void* g, void* l) {
  __builtin_amdgcn_global_load_lds(
      (__attribute__((address_space(1))) void*)g,
      (__attribute__((address_space(3))) void*)l, 16, 0, 0);
}

// ======= prep: conv_x (blocks 0..16383) | conv_w (16384..19455) | ext_qkv (19456..19551) =======
__global__ __launch_bounds__(256) void k_prep(
    const float* __restrict__ x, const float* __restrict__ ext,
    const float* __restrict__ Wq, const float* __restrict__ Wk,
    const float* __restrict__ Wv, const float* __restrict__ Wo,
    const float* __restrict__ bq, const float* __restrict__ bk, const float* __restrict__ bv,
    unsigned short* __restrict__ Xbf, unsigned short* __restrict__ Wqkvt,
    unsigned short* __restrict__ Wot, float* __restrict__ biasqkv,
    float* __restrict__ EQKV) {
  __shared__ float xs[512];
  int bid = blockIdx.x, tid = threadIdx.x;
  if (bid < 16384) {
    // ---- conv_x: fp32 -> bf16, 4 elems/thread ----
    int i = bid * 256 + tid;
    float4 v = ((const float4*)x)[i];
    ((uint2*)Xbf)[i] = make_uint2(pk2(v.x, v.y), pk2(v.z, v.w));
  } else if (bid < 19456) {
    // ---- conv_w: transposed bf16 weights + bias concat ----
    int idx = (bid - 16384) * 256 + tid;
    {
      int nn = idx >> 9, k = idx & 511;
      const float* W = (nn < 512) ? Wq : ((nn < 1024) ? Wk : Wv);
      int n = nn & 511;
      Wqkvt[idx] = f2bf(W[k * 512 + n]);
    }
    if (idx < 512 * 512) {
      int n = idx >> 9, k = idx & 511;
      Wot[idx] = f2bf(Wo[k * 512 + n]);
    }
    if (idx < 1536) {
      biasqkv[idx] = (idx < 512) ? bq[idx] : ((idx < 1024) ? bk[idx - 512] : bv[idx - 1024]);
    }
  } else {
    // ---- ext_qkv: EQKV[16][1536] fp32 (q pre-scaled) ----
    int bid2 = bid - 19456;
    int b = bid2 / 6, c = bid2 % 6;
    int nn = c * 256 + tid;
    xs[tid] = ext[b * 512 + tid];
    xs[256 + tid] = ext[b * 512 + 256 + tid];
    __syncthreads();
    const float* W; const float* bias; float scale = 1.f; int n;
    if (nn < 512)      { W = Wq; bias = bq; n = nn;        scale = ATT_SCALE; }
    else if (nn < 1024){ W = Wk; bias = bk; n = nn - 512; }
    else               { W = Wv; bias = bv; n = nn - 1024; }
    float acc = 0.f;
    #pragma unroll 8
    for (int k = 0; k < 512; ++k) acc += xs[k] * W[k * 512 + n];
    EQKV[b * 1536 + nn] = (acc + bias[n]) * scale;
  }
}

// =============== 128x128-tile MFMA GEMM, m97 2-barrier loop, BK=64, XOR-swizzled LDS ===============
// (round-5/9/12 proven: ~60 us, MfmaUtil 36%, SQ_LDS_BANK_CONFLICT 0) — QKV projection
__global__ __launch_bounds__(256, 2) void k_gemm_qkv(
    const unsigned short* __restrict__ A, const unsigned short* __restrict__ B,
    const float* __restrict__ bias, unsigned short* __restrict__ C) {
  __shared__ __align__(16) unsigned short S[16384];  // A 16 KB + B 16 KB
  int tid = threadIdx.x, lane = tid & 63, wv = tid >> 6;
  int lo = lane & 15, hi = lane >> 4;
  int waveM = wv >> 1, waveN = wv & 1;

  int nwg = gridDim.x;  // 3072
  int wg = (blockIdx.x & 7) * (nwg >> 3) + (blockIdx.x >> 3);
  int bm = wg / 12, bn = wg % 12;

  const unsigned short* Ab = A + (size_t)bm * 128 * 512;
  const unsigned short* Bb = B + (size_t)bn * 128 * 512;
  unsigned short* lA = S;
  unsigned short* lB = S + 8192;

  floatx4 acc[4][4];
  #pragma unroll
  for (int m = 0; m < 4; ++m)
    #pragma unroll
    for (int n = 0; n < 4; ++n) acc[m][n] = floatx4{0.f, 0.f, 0.f, 0.f};

  for (int kt = 0; kt < 8; ++kt) {
    __syncthreads();
    #pragma unroll
    for (int i = 0; i < 4; ++i) {
      int chunk = i * 256 + tid;
      int row = chunk >> 3, slot = chunk & 7;
      glds16(Ab + (size_t)row * 512 + kt * 64 + ((slot ^ (row & 7)) << 3),
             lA + (size_t)(i * 256 + wv * 64) * 8);
    }
    #pragma unroll
    for (int i = 0; i < 4; ++i) {
      int chunk = i * 256 + tid;
      int row = chunk >> 3, slot = chunk & 7;
      glds16(Bb + (size_t)row * 512 + kt * 64 + ((slot ^ (row & 7)) << 3),
             lB + (size_t)(i * 256 + wv * 64) * 8);
    }
    __syncthreads();

    bhalf8 af[4][2], bf4[4][2];
    #pragma unroll
    for (int m = 0; m < 4; ++m) {
      int row = waveM * 64 + m * 16 + lo;
      #pragma unroll
      for (int ks = 0; ks < 2; ++ks)
        af[m][ks] = *(const bhalf8*)(lA + (size_t)row * 64 + (((ks * 4 + hi) ^ (row & 7)) << 3));
    }
    #pragma unroll
    for (int n = 0; n < 4; ++n) {
      int row = waveN * 64 + n * 16 + lo;
      #pragma unroll
      for (int ks = 0; ks < 2; ++ks)
        bf4[n][ks] = *(const bhalf8*)(lB + (size_t)row * 64 + (((ks * 4 + hi) ^ (row & 7)) << 3));
    }
    #pragma unroll
    for (int m = 0; m < 4; ++m)
      #pragma unroll
      for (int n = 0; n < 4; ++n) {
        acc[m][n] = __builtin_amdgcn_mfma_f32_16x16x32_bf16(af[m][0], bf4[n][0], acc[m][n], 0, 0, 0);
        acc[m][n] = __builtin_amdgcn_mfma_f32_16x16x32_bf16(af[m][1], bf4[n][1], acc[m][n], 0, 0, 0);
      }
  }

  #pragma unroll
  for (int m = 0; m < 4; ++m) {
    int row0 = bm * 128 + waveM * 64 + m * 16 + hi * 4;
    #pragma unroll
    for (int n = 0; n < 4; ++n) {
      int col = bn * 128 + waveN * 64 + n * 16 + lo;
      float bb = bias[col];
      #pragma unroll
      for (int r = 0; r < 4; ++r) {
        float v = acc[m][n][r] + bb;
        if (col < 512) v *= ATT_SCALE;
        C[(size_t)(row0 + r) * 1536 + col] = f2bf(v);
      }
    }
  }
}

// ---------------- attention: blocks <1024 = main attn v4; blocks >=1024 = external-query attn ----------------
// VTC=296 (row-12 proven): stride 148 dwords == 20 mod 32 -> 8 consecutive lanes hit
// 8 distinct bank-quads on b128 PV reads (conflict-free); rows 16-B aligned.
#define VTC 296
__global__ __launch_bounds__(512, 4) void k_attn_all(
    const unsigned short* __restrict__ QKV,   // [32768][1536] bf16 (q scaled)
    const float* __restrict__ EQKV,           // [16][1536] f32
    unsigned short* __restrict__ mainb,       // [32768][512] bf16
    float* __restrict__ extpre) {             // [16][512] f32
  __shared__ __align__(16) unsigned short Ks[256 * 64];  // rows XOR-swizzled; reused as epilogue buf
  __shared__ __align__(16) unsigned short Vt[64 * VTC];  // [d][key] transposed, local keys only
  __shared__ float kx[64], vx[64];
  int tid = threadIdx.x, lane = tid & 63, wv = tid >> 6;

  if (blockIdx.x >= 1024) {
    // ======== external-query attention, 512 threads, keys 0..256 of chunk j=1 ========
    int eg = blockIdx.x - 1024;
    int b = eg >> 3, h = eg & 7;
    float* qs   = (float*)Ks;          // 64
    float* ps   = qs + 64;             // 257
    float* redm = ps + 257;            // 8
    float* reds = redm + 8;            // 8
    float (*acc8)[64] = (float (*)[64])(reds + 8);  // 8x64
    if (tid < 64) qs[tid] = EQKV[b * 1536 + h * 64 + tid];
    __syncthreads();
    const size_t base = (size_t)b * 2048 + 256;
    float s = -1e30f;
    if (tid < 257) {
      s = 0.f;
      if (tid == 0) {
        const float* kr = EQKV + b * 1536 + 512 + h * 64;
        #pragma unroll 8
        for (int d = 0; d < 64; ++d) s += qs[d] * kr[d];
      } else {
        const unsigned short* kr = QKV + (base + tid - 1) * 1536 + 512 + h * 64;
        #pragma unroll
        for (int c = 0; c < 8; ++c) {
          ush8 kv = *(const ush8*)(kr + c * 8);
          #pragma unroll
          for (int u = 0; u < 8; ++u) s += qs[c * 8 + u] * bf2f(kv[u]);
        }
      }
    }
    float lmax = s;
    for (int d = 1; d < 64; d <<= 1) lmax = fmaxf(lmax, __shfl_xor(lmax, d, 64));
    if (lane == 0) redm[wv] = lmax;
    __syncthreads();
    float M = redm[0];
    #pragma unroll
    for (int w = 1; w < 8; ++w) M = fmaxf(M, redm[w]);
    float p = 0.f;
    if (tid < 257) { p = __expf(s - M); ps[tid] = p; }
    float lsum = p;
    for (int d = 1; d < 64; d <<= 1) lsum += __shfl_xor(lsum, d, 64);
    if (lane == 0) reds[wv] = lsum;
    __syncthreads();
    float Ssum = reds[0] + reds[1] + reds[2] + reds[3] + reds[4] + reds[5] + reds[6] + reds[7];
    int d = tid & 63, part = tid >> 6;
    float acc = 0.f;
    for (int key = part; key < 257; key += 8) {
      float vv = (key == 0) ? EQKV[b * 1536 + 1024 + h * 64 + d]
                            : bf2f(QKV[(base + key - 1) * 1536 + 1024 + h * 64 + d]);
      acc += ps[key] * vv;
    }
    acc8[part][d] = acc;
    __syncthreads();
    if (tid < 64) {
      float r = (acc8[0][tid] + acc8[1][tid] + acc8[2][tid] + acc8[3][tid] +
                 acc8[4][tid] + acc8[5][tid] + acc8[6][tid] + acc8[7][tid]) / Ssum;
      extpre[b * 512 + h * 64 + tid] = r;
    }
    return;
  }

  // ======== main attention v4: 8 warps x 32 queries; local keys 0..255; external key in-register ========
  int g = blockIdx.x;
  int b = g >> 6, h = (g >> 3) & 7, j = g & 7;
  int ql = lane & 31, hb = lane >> 5;
  const size_t rowbase = (size_t)b * 2048 + (size_t)j * 256;
  const unsigned short* Kg = QKV + rowbase * 1536 + 512 + h * 64;
  const unsigned short* Vg = QKV + rowbase * 1536 + 1024 + h * 64;

  int qbase = wv * 32;
  const unsigned short* qp = QKV + (rowbase + qbase + ql) * 1536 + h * 64 + hb * 8;
  bhalf8 qf[4];
  #pragma unroll
  for (int c = 0; c < 4; ++c) qf[c] = *(const bhalf8*)(qp + c * 16);

  // stage K rows 0..255 via global_load_lds, pre-swizzled source (linear dest)
  {
    int keybase = wv * 32;
    #pragma unroll
    for (int i = 0; i < 4; ++i) {
      int key = keybase + i * 8 + (lane >> 3);
      int slot = lane & 7;
      const unsigned short* src =
          Kg + (size_t)key * 1536 + (((slot * 16) ^ ((key & 7) << 4)) >> 1);
      glds16(src, &Ks[(size_t)(keybase + i * 8) * 64]);
    }
  }
  // stage V transposed: lanes of one instr cover 64 different KEYS -> 2-way banks (free)
  for (int c = tid; c < 2048; c += 512) {
    int key = c & 255, d0 = (c >> 8) * 8;
    ush8 vv = *(const ush8*)(Vg + (size_t)key * 1536 + d0);
    #pragma unroll
    for (int u = 0; u < 8; ++u) Vt[(d0 + u) * VTC + key] = vv[u];
  }
  if (tid < 64) {
    kx[tid] = EQKV[b * 1536 + 512 + h * 64 + tid];
    vx[tid] = EQKV[b * 1536 + 1024 + h * 64 + tid];
  }
  __syncthreads();

  // external-key score: lane holds q[ql] dims {c*16+hb*8 .. +7}; partner has the rest
  float part = 0.f;
  #pragma unroll
  for (int c = 0; c < 4; ++c)
    #pragma unroll
    for (int u = 0; u < 8; ++u)
      part += bf2f((unsigned short)qf[c][u]) * kx[c * 16 + hb * 8 + u];
  float m = part + __shfl_xor(part, 32, 64);   // s_ext (q pre-scaled)
  float lsum = 1.f;                            // exp(s_ext - m) = 1
  floatx16 o0, o1;
  #pragma unroll
  for (int i = 0; i < 8; ++i) {                // o init = p_ext * v_ext = v_ext
    int d0 = ((2 * i) & 3) + 8 * (i >> 1) + 4 * hb;
    o0[2 * i] = vx[d0];       o0[2 * i + 1] = vx[d0 + 1];
    o1[2 * i] = vx[32 + d0];  o1[2 * i + 1] = vx[32 + d0 + 1];
  }

  #pragma unroll
  for (int t = 0; t < 8; ++t) {
    floatx16 s;
    #pragma unroll
    for (int i = 0; i < 16; ++i) s[i] = 0.f;
    int key = t * 32 + ql;
    __builtin_amdgcn_s_setprio(1);
    #pragma unroll
    for (int c = 0; c < 4; ++c) {
      bhalf8 kf = *(const bhalf8*)((const char*)Ks + key * 128 +
                                   ((c * 32 + hb * 16) ^ ((key & 7) << 4)));
      s = __builtin_amdgcn_mfma_f32_32x32x16_bf16(kf, qf[c], s, 0, 0, 0);
    }
    __builtin_amdgcn_s_setprio(0);
    float mt = s[0];
    #pragma unroll
    for (int r = 1; r < 16; ++r) mt = fmaxf(mt, s[r]);
    mt = fmaxf(mt, __shfl_xor(mt, 32, 64));
    if (!__all(mt - m <= 8.f)) {   // defer-max (T13)
      float mnew = fmaxf(m, mt);
      float corr = __expf(m - mnew);
      lsum *= corr;
      #pragma unroll
      for (int r = 0; r < 16; ++r) { o0[r] *= corr; o1[r] *= corr; }
      m = mnew;
    }
    float p[16]; float ts = 0.f;
    #pragma unroll
    for (int r = 0; r < 16; ++r) { p[r] = __expf(s[r] - m); ts += p[r]; }
    lsum += ts;
    unsigned int pk[8], qk[8];
    #pragma unroll
    for (int i = 0; i < 8; ++i) pk[i] = pk2(p[2 * i], p[2 * i + 1]);
    #pragma unroll
    for (int i = 0; i < 8; ++i) qk[i] = __shfl_xor(pk[i], 32, 64);
    bhalf8 f0, f1;
    unsigned int* f0u = (unsigned int*)&f0;
    unsigned int* f1u = (unsigned int*)&f1;
    if (hb == 0) {
      f0u[0] = pk[0]; f0u[1] = pk[1]; f0u[2] = qk[0]; f0u[3] = qk[1];
      f1u[0] = pk[4]; f1u[1] = pk[5]; f1u[2] = qk[4]; f1u[3] = qk[5];
    } else {
      f0u[0] = qk[2]; f0u[1] = qk[3]; f0u[2] = pk[2]; f0u[3] = pk[3];
      f1u[0] = qk[6]; f1u[1] = qk[7]; f1u[2] = pk[6]; f1u[3] = pk[7];
    }
    {
      const char* vb0 = (const char*)Vt + ((0 * 32 + ql) * VTC + t * 32 + hb * 8) * 2;
      bhalf8 v0 = *(const bhalf8*)vb0;
      bhalf8 v1 = *(const bhalf8*)(vb0 + 32);
      const char* vb1 = (const char*)Vt + ((1 * 32 + ql) * VTC + t * 32 + hb * 8) * 2;
      bhalf8 w0 = *(const bhalf8*)vb1;
      bhalf8 w1 = *(const bhalf8*)(vb1 + 32);
      __builtin_amdgcn_s_setprio(1);
      o0 = __builtin_amdgcn_mfma_f32_32x32x16_bf16(v0, f0, o0, 0, 0, 0);
      o0 = __builtin_amdgcn_mfma_f32_32x32x16_bf16(v1, f1, o0, 0, 0, 0);
      o1 = __builtin_amdgcn_mfma_f32_32x32x16_bf16(w0, f0, o1, 0, 0, 0);
      o1 = __builtin_amdgcn_mfma_f32_32x32x16_bf16(w1, f1, o1, 0, 0, 0);
      __builtin_amdgcn_s_setprio(0);
    }
  }

  lsum += __shfl_xor(lsum, 32, 64);
  float rinv = 1.f / lsum;
  __syncthreads();  // all K reads done; reuse Ks as per-warp transpose buffer
  char* ob = (char*)(Ks + wv * 2048);  // 32q x 64d bf16 = 4KB per warp
  #pragma unroll
  for (int dt = 0; dt < 2; ++dt) {
    #pragma unroll
    for (int i = 0; i < 8; ++i) {
      int d0 = dt * 32 + ((2 * i) & 3) + 8 * (i >> 1) + 4 * hb;
      float a = (dt ? o1[2 * i] : o0[2 * i]) * rinv;
      float c = (dt ? o1[2 * i + 1] : o0[2 * i + 1]) * rinv;
      *(unsigned int*)(ob + ql * 128 + ((d0 * 2) ^ ((ql & 7) << 4))) = pk2(a, c);
    }
  }
  #pragma unroll
  for (int i = 0; i < 4; ++i) {
    int chunk = i * 64 + lane;
    int q = chunk >> 3, slot = chunk & 7;
    bhalf8 vv = *(const bhalf8*)(ob + q * 128 + ((slot * 16) ^ ((q & 7) << 4)));
    *(bhalf8*)(mainb + (rowbase + qbase + q) * 512 + h * 64 + slot * 8) = vv;
  }
}

// ======= output GEMM (wg<1024) | ext_out (wg>=1024): C f32 = mainb * Wo^T + bo =======
__global__ __launch_bounds__(256, 2) void k_gemm_out(
    const unsigned short* __restrict__ A, const unsigned short* __restrict__ B,
    const float* __restrict__ bias, float* __restrict__ C,
    const float* __restrict__ extpre, const float* __restrict__ Wo) {
  __shared__ __align__(16) unsigned short S[16384];
  int tid = threadIdx.x, lane = tid & 63, wv = tid >> 6;
  int nwg = gridDim.x;  // 1056, %8==0
  int wg = (blockIdx.x & 7) * (nwg >> 3) + (blockIdx.x >> 3);

  if (wg >= 1024) {
    // ---- ext_out: out[16M + b*512 + n] = extpre[b] . Wo[:,n] + bo[n] ----
    int idx = wg - 1024;            // 0..31
    int b = idx >> 1, half = idx & 1;
    int n = half * 256 + tid;
    float* xs = (float*)S;
    xs[tid] = extpre[b * 512 + tid];
    xs[256 + tid] = extpre[b * 512 + 256 + tid];
    __syncthreads();
    float acc = bias[n];
    #pragma unroll 8
    for (int k = 0; k < 512; ++k) acc += xs[k] * Wo[k * 512 + n];
    C[16777216 + b * 512 + n] = acc;
    return;
  }

  int lo = lane & 15, hi = lane >> 4;
  int waveM = wv >> 1, waveN = wv & 1;
  int bm = wg / 4, bn = wg % 4;

  const unsigned short* Ab = A + (size_t)bm * 128 * 512;
  const unsigned short* Bb = B + (size_t)bn * 128 * 512;
  unsigned short* lA = S;
  unsigned short* lB = S + 8192;

  floatx4 acc[4][4];
  #pragma unroll
  for (int m = 0; m < 4; ++m)
    #pragma unroll
    for (int n = 0; n < 4; ++n) acc[m][n] = floatx4{0.f, 0.f, 0.f, 0.f};

  for (int kt = 0; kt < 8; ++kt) {
    __syncthreads();
    #pragma unroll
    for (int i = 0; i < 4; ++i) {
      int chunk = i * 256 + tid;
      int row = chunk >> 3, slot = chunk & 7;
      glds16(Ab + (size_t)row * 512 + kt * 64 + ((slot ^ (row & 7)) << 3),
             lA + (size_t)(i * 256 + wv * 64) * 8);
    }
    #pragma unroll
    for (int i = 0; i < 4; ++i) {
      int chunk = i * 256 + tid;
      int row = chunk >> 3, slot = chunk & 7;
      glds16(Bb + (size_t)row * 512 + kt * 64 + ((slot ^ (row & 7)) << 3),
             lB + (size_t)(i * 256 + wv * 64) * 8);
    }
    __syncthreads();

    bhalf8 af[4][2], bf4[4][2];
    #pragma unroll
    for (int m = 0; m < 4; ++m) {
      int row = waveM * 64 + m * 16 + lo;
      #pragma unroll
      for (int ks = 0; ks < 2; ++ks)
        af[m][ks] = *(const bhalf8*)(lA + (size_t)row * 64 + (((ks * 4 + hi) ^ (row & 7)) << 3));
    }
    #pragma unroll
    for (int n = 0; n < 4; ++n) {
      int row = waveN * 64 + n * 16 + lo;
      #pragma unroll
      for (int ks = 0; ks < 2; ++ks)
        bf4[n][ks] = *(const bhalf8*)(lB + (size_t)row * 64 + (((ks * 4 + hi) ^ (row & 7)) << 3));
    }
    #pragma unroll
    for (int m = 0; m < 4; ++m)
      #pragma unroll
      for (int n = 0; n < 4; ++n) {
        acc[m][n] = __builtin_amdgcn_mfma_f32_16x16x32_bf16(af[m][0], bf4[n][0], acc[m][n], 0, 0, 0);
        acc[m][n] = __builtin_amdgcn_mfma_f32_16x16x32_bf16(af[m][1], bf4[n][1], acc[m][n], 0, 0, 0);
      }
  }

  #pragma unroll
  for (int m = 0; m < 4; ++m) {
    int row0 = bm * 128 + waveM * 64 + m * 16 + hi * 4;
    #pragma unroll
    for (int n = 0; n < 4; ++n) {
      int col = bn * 128 + waveN * 64 + n * 16 + lo;
      float bb = bias[col];
      #pragma unroll
      for (int r = 0; r < 4; ++r)
        C[(size_t)(row0 + r) * 512 + col] = acc[m][n][r] + bb;
    }
  }
}

extern "C" void kernel_launch(void* const* d_in, const int* in_sizes, int n_in,
                              void* d_out, int out_size, void* d_ws, size_t ws_size,
                              hipStream_t stream) {
  (void)in_sizes; (void)n_in; (void)out_size; (void)ws_size;
  const float* x   = (const float*)d_in[0];
  const float* ext = (const float*)d_in[1];
  const float* Wq  = (const float*)d_in[2];
  const float* bq  = (const float*)d_in[3];
  const float* Wk  = (const float*)d_in[4];
  const float* bk  = (const float*)d_in[5];
  const float* Wv  = (const float*)d_in[6];
  const float* bv  = (const float*)d_in[7];
  const float* Wo  = (const float*)d_in[8];
  const float* bo  = (const float*)d_in[9];
  float* out = (float*)d_out;

  char* ws = (char*)d_ws;
  size_t off = 0;
  auto take = [&](size_t bytes) { char* p = ws + off; off += (bytes + 255) & ~(size_t)255; return p; };
  unsigned short* Xbf    = (unsigned short*)take((size_t)32768 * 512 * 2);
  unsigned short* Wqkvt  = (unsigned short*)take((size_t)1536 * 512 * 2);
  unsigned short* Wot    = (unsigned short*)take((size_t)512 * 512 * 2);
  float*          biasqkv= (float*)take(1536 * 4);
  float*          EQKV   = (float*)take(16 * 1536 * 4);
  unsigned short* QKVb   = (unsigned short*)take((size_t)32768 * 1536 * 2);
  unsigned short* mainb  = (unsigned short*)take((size_t)32768 * 512 * 2);
  float*          extpre = (float*)take(16 * 512 * 4);

  k_prep<<<19552, 256, 0, stream>>>(x, ext, Wq, Wk, Wv, Wo, bq, bk, bv,
                                    Xbf, Wqkvt, Wot, biasqkv, EQKV);
  k_gemm_qkv<<<3072, 256, 0, stream>>>(Xbf, Wqkvt, biasqkv, QKVb);
  k_attn_all<<<1152, 512, 0, stream>>>(QKVb, EQKV, mainb, extpre);
  k_gemm_out<<<1056, 256, 0, stream>>>(mainb, Wot, bo, out, extpre, Wo);
}